// Round 10
// baseline (261.999 us; speedup 1.0000x reference)
//
#include <hip/hip_runtime.h>
#include <math.h>

#define BB 2
#define SS 2048
#define DD 1024
#define HH 16
#define DHD 64
#define N3 3072
#define LN_EPS 1e-5f

#define PLANE (BB*HH*SS*DHD)   // 4194304 elements per q/k/v plane

typedef __attribute__((ext_vector_type(8))) short bf16x8;
typedef __attribute__((ext_vector_type(4))) float f32x4;
typedef unsigned int u32;
typedef unsigned short ushort_t;

// fp32 -> bf16 round-to-nearest-even (finite inputs only)
static __device__ __forceinline__ short f2bf(float f) {
  union { float f; unsigned u; } a;
  a.f = f;
  unsigned r = a.u + 0x7fffu + ((a.u >> 16) & 1u);
  return (short)(r >> 16);
}

static __device__ __forceinline__ u32 fbits(float f) {
  union { float f; u32 u; } a; a.f = f; return a.u;
}

// async global->LDS, 16 bytes per lane; lds dest = base + lane*16 (wave-uniform base)
static __device__ __forceinline__ void gload_lds16(const void* g, void* l) {
  __builtin_amdgcn_global_load_lds(
      (const __attribute__((address_space(1))) u32*)g,
      (__attribute__((address_space(3))) u32*)l, 16, 0, 0);
}

// ---------------------------------------------------------------------------
// Fused prep kernel: grid-range dispatch.
// ---------------------------------------------------------------------------
#define PREP_CONV_B   2048
#define PREP_TA_B     768     // (3072/64)*(1024/64)
#define PREP_TO_B     256     // (1024/64)*(1024/64)
#define PREP_PACK_B   32768   // BB*SS*SS/256
#define PREP_TOTAL_B  (PREP_CONV_B + PREP_TA_B + PREP_TO_B + PREP_PACK_B)

__global__ __launch_bounds__(256) void prep_kernel(
    const float* __restrict__ x, ushort_t* __restrict__ xb,
    const float* __restrict__ Wa, ushort_t* __restrict__ watt,
    const float* __restrict__ Wo, ushort_t* __restrict__ wot,
    const int* __restrict__ mask, unsigned long long* __restrict__ bits) {
  __shared__ float tile[64][65];
  const int tid = threadIdx.x;
  const int bid = blockIdx.x;

  if (bid < PREP_CONV_B) {
    int i = (bid * 256 + tid) * 8;
    float4 a = *(const float4*)&x[i];
    float4 b = *(const float4*)&x[i + 4];
    short s[8] = {f2bf(a.x), f2bf(a.y), f2bf(a.z), f2bf(a.w),
                  f2bf(b.x), f2bf(b.y), f2bf(b.z), f2bf(b.w)};
    *(bf16x8*)&xb[i] = *(bf16x8*)s;
    return;
  }
  if (bid < PREP_CONV_B + PREP_TA_B + PREP_TO_B) {
    const float* W; ushort_t* Wt; int K, N, nb, kb;
    if (bid < PREP_CONV_B + PREP_TA_B) {
      int idx = bid - PREP_CONV_B;
      W = Wa; Wt = watt; K = DD; N = N3;
      nb = (idx % 48) * 64; kb = (idx / 48) * 64;
    } else {
      int idx = bid - PREP_CONV_B - PREP_TA_B;
      W = Wo; Wt = wot; K = DD; N = DD;
      nb = (idx % 16) * 64; kb = (idx / 16) * 64;
    }
    #pragma unroll
    for (int i = 0; i < 4; ++i) {
      int idx = tid + i * 256;
      int r = idx >> 4, c = (idx & 15) * 4;
      float4 v = *(const float4*)&W[(size_t)(kb + r) * N + nb + c];
      tile[r][c] = v.x; tile[r][c + 1] = v.y;
      tile[r][c + 2] = v.z; tile[r][c + 3] = v.w;
    }
    __syncthreads();
    #pragma unroll
    for (int i = 0; i < 4; ++i) {
      int idx = tid + i * 256;
      int n = idx >> 4, k = (idx & 15) * 4;
      short4 s;
      s.x = f2bf(tile[k][n]); s.y = f2bf(tile[k + 1][n]);
      s.z = f2bf(tile[k + 2][n]); s.w = f2bf(tile[k + 3][n]);
      *(short4*)&Wt[(size_t)(nb + n) * K + kb + k] = s;
    }
    return;
  }
  {
    size_t g = (size_t)(bid - PREP_CONV_B - PREP_TA_B - PREP_TO_B) * 256 + tid;
    int m = mask[g];
    unsigned long long b = __ballot(m != 0);
    if ((tid & 63) == 0) bits[g >> 6] = b;
  }
}

// ===========================================================================
// m97-style bf16 MFMA GEMM core. R9: OPERAND-SWAPPED MFMA (mfma(bfr, af)) ->
// C^T register layout: each lane holds C[row = tile + lane16]
// [cols = tile + quad*4 + reg] -> vectorized epilogue stores.
// Fragment reads identical (A/B operands share the same lane map; R8-verified).
// ===========================================================================
#define GEMM_MAIN(Aptr, Btptr, Kdim)                                          \
  __shared__ ushort_t As[128 * 64];                                           \
  __shared__ ushort_t Bs[128 * 64];                                           \
  const int tid = threadIdx.x;                                                \
  const int wave = tid >> 6, lane = tid & 63;                                 \
  const int lane16 = lane & 15, quad = lane >> 4;                             \
  const int wm = wave & 1, wn = wave >> 1;                                    \
  const int bm = blockIdx.y * 128, bn = blockIdx.x * 128;                     \
  const int srow = lane >> 3;                                                 \
  const int sg = (lane & 7) ^ srow;                                           \
  f32x4 acc[4][4];                                                            \
  _Pragma("unroll") for (int i = 0; i < 4; ++i)                               \
    _Pragma("unroll") for (int j = 0; j < 4; ++j)                             \
      acc[i][j] = (f32x4){0.f, 0.f, 0.f, 0.f};                                \
  const ushort_t* agp[4];                                                     \
  const ushort_t* bgp[4];                                                     \
  _Pragma("unroll") for (int i = 0; i < 4; ++i) {                             \
    int seg = wave * 4 + i;                                                   \
    int r = seg * 8 + srow;                                                   \
    agp[i] = Aptr + (size_t)(bm + r) * Kdim + sg * 8;                         \
    bgp[i] = Btptr + (size_t)(bn + r) * Kdim + sg * 8;                        \
  }                                                                           \
  for (int k0 = 0; k0 < Kdim; k0 += 64) {                                     \
    _Pragma("unroll") for (int i = 0; i < 4; ++i) {                           \
      int seg = wave * 4 + i;                                                 \
      gload_lds16(agp[i] + k0, &As[seg * 512]);                               \
      gload_lds16(bgp[i] + k0, &Bs[seg * 512]);                               \
    }                                                                         \
    __syncthreads();                                                          \
    _Pragma("unroll") for (int ks = 0; ks < 2; ++ks) {                        \
      bf16x8 af[4], bfr[4];                                                   \
      _Pragma("unroll") for (int mt = 0; mt < 4; ++mt) {                      \
        int ra = wm * 64 + mt * 16 + lane16;                                  \
        int kc = ks * 4 + quad;                                               \
        af[mt] = *(const bf16x8*)&As[ra * 64 + ((kc ^ (ra & 7)) * 8)];        \
      }                                                                       \
      _Pragma("unroll") for (int nt = 0; nt < 4; ++nt) {                      \
        int rb = wn * 64 + nt * 16 + lane16;                                  \
        int kc = ks * 4 + quad;                                               \
        bfr[nt] = *(const bf16x8*)&Bs[rb * 64 + ((kc ^ (rb & 7)) * 8)];       \
      }                                                                       \
      _Pragma("unroll") for (int mt = 0; mt < 4; ++mt)                        \
        _Pragma("unroll") for (int nt = 0; nt < 4; ++nt)                      \
          acc[mt][nt] = __builtin_amdgcn_mfma_f32_16x16x32_bf16(              \
              bfr[nt], af[mt], acc[mt][nt], 0, 0, 0);                         \
    }                                                                         \
    __syncthreads();                                                          \
  }

// ---------------------------------------------------------------------------
// GEMM 1: qkv -> bf16 head-major q/k/v [B,H,S,DH].
// R9 epilogue: C^T layout -> 16 short4 stores (4 consecutive d per lane).
// ---------------------------------------------------------------------------
__global__ __launch_bounds__(256) void gemm_qkv_mfma(
    const ushort_t* __restrict__ A, const ushort_t* __restrict__ Bt,
    const float* __restrict__ bias, ushort_t* __restrict__ qkvh) {
  GEMM_MAIN(A, Bt, DD)
  #pragma unroll
  for (int nt = 0; nt < 4; ++nt) {
    int col0 = bn + wn * 64 + nt * 16 + quad * 4;
    int which = col0 >> 10, hcol = col0 & 1023;
    int head = hcol >> 6, d0 = hcol & 63;
    float4 b4 = *(const float4*)&bias[col0];
    ushort_t* plane = qkvh + (size_t)which * PLANE;
    #pragma unroll
    for (int mt = 0; mt < 4; ++mt) {
      int row = bm + wm * 64 + mt * 16 + lane16;
      int bb = row >> 11, ss = row & (SS - 1);
      short4 s4;
      s4.x = f2bf(acc[mt][nt][0] + b4.x);
      s4.y = f2bf(acc[mt][nt][1] + b4.y);
      s4.z = f2bf(acc[mt][nt][2] + b4.z);
      s4.w = f2bf(acc[mt][nt][3] + b4.w);
      *(short4*)&plane[((size_t)(bb * HH + head) * SS + ss) * DHD + d0] = s4;
    }
  }
}

// ---------------------------------------------------------------------------
// GEMM 2: y = x + attnb @ W_out + b_out -> fp32 d_out.
// R9 epilogue: C^T layout -> float4 xres loads + float4 stores, coalesced.
// ---------------------------------------------------------------------------
__global__ __launch_bounds__(256) void gemm_proj_mfma(
    const ushort_t* __restrict__ A, const ushort_t* __restrict__ Bt,
    const float* __restrict__ bias, const float* __restrict__ xres,
    float* __restrict__ Y) {
  GEMM_MAIN(A, Bt, DD)
  #pragma unroll
  for (int nt = 0; nt < 4; ++nt) {
    int col0 = bn + wn * 64 + nt * 16 + quad * 4;
    float4 b4 = *(const float4*)&bias[col0];
    #pragma unroll
    for (int mt = 0; mt < 4; ++mt) {
      int row = bm + wm * 64 + mt * 16 + lane16;
      float4 xr = *(const float4*)&xres[(size_t)row * DD + col0];
      float4 v;
      v.x = acc[mt][nt][0] + b4.x + xr.x;
      v.y = acc[mt][nt][1] + b4.y + xr.y;
      v.z = acc[mt][nt][2] + b4.z + xr.z;
      v.w = acc[mt][nt][3] + b4.w + xr.w;
      *(float4*)&Y[(size_t)row * DD + col0] = v;
    }
  }
}

// ---------------------------------------------------------------------------
// bf16 MFMA flash attention (R8-verified, byte-identical this round).
// ---------------------------------------------------------------------------
__global__ __launch_bounds__(512) void attn_mfma_kernel(
    const ushort_t* __restrict__ qh, const ushort_t* __restrict__ kh,
    const ushort_t* __restrict__ vh, const u32* __restrict__ mbits,
    ushort_t* __restrict__ attn_out) {
  __shared__ __align__(16) short Kt[2][64][76];     // K[k][d], two 64-halves
  __shared__ __align__(16) short Vt[2][64][76];     // V^T[d][k], two halves
  __shared__ __align__(16) short Pt[8][16][76];     // per-wave P[m=q][k]

  const int tid = threadIdx.x;
  const int wave = tid >> 6, lane = tid & 63;
  const int lane16 = lane & 15, quad = lane >> 4;

  const int bh = blockIdx.x & 31;          // b*16 + h  (L2: head -> one XCD)
  const int qt = blockIdx.x >> 5;          // q tile of 128 (16 tiles)
  const int bbi = bh >> 4, hhi = bh & 15;
  const size_t head_base = (size_t)bh * SS * DHD;
  const int q0 = qt * 128 + wave * 16;
  const int qrow_g = q0 + quad * 4;        // epilogue rows (C layout of PV)

  // Q fragments, pre-scaled by log2(e)/sqrt(DH) so exp(s)=2^(s').
  bf16x8 qf[2];
  {
    const float kScale = 0.125f * 1.44269504f;
    const ushort_t* qsrc = &qh[head_base + (size_t)(q0 + lane16) * DHD + quad * 8];
    #pragma unroll
    for (int ks = 0; ks < 2; ++ks) {
      bf16x8 r = *(const bf16x8*)&qsrc[ks * 32];
      #pragma unroll
      for (int e = 0; e < 8; ++e) {
        union { u32 u; float f; } c;
        c.u = ((u32)(ushort_t)r[e]) << 16;
        c.f *= kScale;
        r[e] = f2bf(c.f);
      }
      qf[ks] = r;
    }
  }

  // ones B-fragment for l row-sum MFMA (bf16 1.0 = 0x3F80)
  bf16x8 onesf;
  #pragma unroll
  for (int e = 0; e < 8; ++e) onesf[e] = (short)0x3F80;

  f32x4 acc[4];
  f32x4 lacc = (f32x4){0.f, 0.f, 0.f, 0.f};
  #pragma unroll
  for (int dt = 0; dt < 4; ++dt) acc[dt] = (f32x4){0.f, 0.f, 0.f, 0.f};

  // softmax q-row for THIS thread (S^T layout): q0 + lane16
  const u32* mrow = mbits + ((size_t)(bbi * SS) + q0 + lane16) * 64;
  const int shq = quad * 4;

  // staging-thread geometry (512 threads, 128-row tile)
  const int kg_r = tid >> 3;               // 0..63
  const int kg_c = (tid & 7) * 8;
  const int vs_c = tid & 63;
  const int v_half = wave >> 2;
  const int vs_rb_l = (wave & 3) * 16;     // local row base within half
  const int vs_rb_g = wave * 16;           // global row base within 128-tile

  // prefetch registers for tile kt=0
  bf16x8 kreg[2];
  short4 vreg[4];
  uint4 mwn;
  {
    #pragma unroll
    for (int i = 0; i < 2; ++i)
      kreg[i] = *(const bf16x8*)&kh[head_base + (size_t)(kg_r + i * 64) * DHD + kg_c];
    #pragma unroll
    for (int i = 0; i < 4; ++i) {
      int r0 = vs_rb_g + i * 4;
      const ushort_t* vsrc = &vh[head_base + (size_t)r0 * DHD + vs_c];
      vreg[i].x = (short)vsrc[0];
      vreg[i].y = (short)vsrc[DHD];
      vreg[i].z = (short)vsrc[2 * DHD];
      vreg[i].w = (short)vsrc[3 * DHD];
    }
    mwn = *(const uint4*)&mrow[0];
  }

  for (int kt = 0; kt < SS; kt += 128) {
    __syncthreads();   // all waves done reading prev Kt/Vt
    #pragma unroll
    for (int i = 0; i < 2; ++i)
      *(bf16x8*)&Kt[i][kg_r][kg_c] = kreg[i];
    #pragma unroll
    for (int i = 0; i < 4; ++i)
      *(short4*)&Vt[v_half][vs_c][vs_rb_l + i * 4] = vreg[i];
    uint4 mwc = mwn;
    __syncthreads();   // staging visible

    // issue next 128-tile's global loads; latency drains under MFMA/exp
    const int kt2 = kt + 128;
    if (kt2 < SS) {
      #pragma unroll
      for (int i = 0; i < 2; ++i)
        kreg[i] = *(const bf16x8*)&kh[head_base + (size_t)(kt2 + kg_r + i * 64) * DHD + kg_c];
      #pragma unroll
      for (int i = 0; i < 4; ++i) {
        int r0 = kt2 + vs_rb_g + i * 4;
        const ushort_t* vsrc = &vh[head_base + (size_t)r0 * DHD + vs_c];
        vreg[i].x = (short)vsrc[0];
        vreg[i].y = (short)vsrc[DHD];
        vreg[i].z = (short)vsrc[2 * DHD];
        vreg[i].w = (short)vsrc[3 * DHD];
      }
      mwn = *(const uint4*)&mrow[kt2 >> 5];
    }

    // two 64-halves
    #pragma unroll
    for (int h = 0; h < 2; ++h) {
      // S^T = K·Q^T: C col = lane16 = q-row, C row = quad*4+reg = k-col
      f32x4 sc[4];
      #pragma unroll
      for (int nt = 0; nt < 4; ++nt) {
        sc[nt] = (f32x4){0.f, 0.f, 0.f, 0.f};
        #pragma unroll
        for (int ks = 0; ks < 2; ++ks) {
          bf16x8 kf = *(const bf16x8*)&Kt[h][nt * 16 + lane16][ks * 32 + quad * 8];
          sc[nt] = __builtin_amdgcn_mfma_f32_16x16x32_bf16(kf, qf[ks], sc[nt], 0, 0, 0);
        }
      }

      // p = mask ? 0 : 2^(s'); thread covers k = nt*16 + quad*4 + reg
      const u32 wlo = h ? mwc.z : mwc.x;
      const u32 whi = h ? mwc.w : mwc.y;
      const u32 tl = wlo >> shq;
      const u32 th = whi >> shq;
      #pragma unroll
      for (int nt = 0; nt < 4; ++nt) {
        const u32 w = (nt & 2) ? th : tl;
        const u32 base = (nt & 1) ? 0x10000u : 1u;
        float e0 = (w & (base << 0)) ? 0.f : exp2f(sc[nt][0]);
        float e1 = (w & (base << 1)) ? 0.f : exp2f(sc[nt][1]);
        float e2 = (w & (base << 2)) ? 0.f : exp2f(sc[nt][2]);
        float e3 = (w & (base << 3)) ? 0.f : exp2f(sc[nt][3]);
        u32 w0 = __builtin_amdgcn_perm(fbits(e1) + 0x8000u, fbits(e0) + 0x8000u,
                                       0x07060302u);
        u32 w1 = __builtin_amdgcn_perm(fbits(e3) + 0x8000u, fbits(e2) + 0x8000u,
                                       0x07060302u);
        uint2 pw; pw.x = w0; pw.y = w1;
        *(uint2*)&Pt[wave][lane16][nt * 16 + shq] = pw;
      }
      // no barrier: Pt[wave] is wave-private; same-wave DS ops are in-order

      // P·V (+ l row-sum via ones fragment)
      #pragma unroll
      for (int ks = 0; ks < 2; ++ks) {
        bf16x8 pf = *(const bf16x8*)&Pt[wave][lane16][ks * 32 + quad * 8];
        lacc = __builtin_amdgcn_mfma_f32_16x16x32_bf16(pf, onesf, lacc, 0, 0, 0);
        #pragma unroll
        for (int dt = 0; dt < 4; ++dt) {
          bf16x8 vf = *(const bf16x8*)&Vt[h][dt * 16 + lane16][ks * 32 + quad * 8];
          acc[dt] = __builtin_amdgcn_mfma_f32_16x16x32_bf16(pf, vf, acc[dt], 0, 0, 0);
        }
      }
    }
  }

  // epilogue: normalize by l, store bf16 to attn [B, S, H*DH]
  #pragma unroll
  for (int reg = 0; reg < 4; ++reg) {
    float inv = 1.0f / lacc[reg];
    ushort_t* orow = &attn_out[((size_t)(bbi * SS) + qrow_g + reg) * DD
                               + hhi * DHD + lane16];
    #pragma unroll
    for (int dt = 0; dt < 4; ++dt)
      orow[dt * 16] = (ushort_t)f2bf(acc[dt][reg] * inv);
  }
}

// ---------------------------------------------------------------------------
// in-place LayerNorm over D=1024 per row
// ---------------------------------------------------------------------------
__global__ __launch_bounds__(256) void ln_kernel(
    float* __restrict__ Y, const float* __restrict__ g,
    const float* __restrict__ bta) {
  const int r = blockIdx.x;
  const int tid = threadIdx.x;
  float4 v = *(const float4*)&Y[(size_t)r * DD + tid * 4];
  float sum = v.x + v.y + v.z + v.w;
  float sq = v.x * v.x + v.y * v.y + v.z * v.z + v.w * v.w;
  #pragma unroll
  for (int off = 32; off; off >>= 1) {
    sum += __shfl_down(sum, off);
    sq += __shfl_down(sq, off);
  }
  __shared__ float ps[4], pq[4];
  __shared__ float mu_s, rs_s;
  const int wave = tid >> 6;
  if ((tid & 63) == 0) { ps[wave] = sum; pq[wave] = sq; }
  __syncthreads();
  if (tid == 0) {
    float s = ps[0] + ps[1] + ps[2] + ps[3];
    float qq = pq[0] + pq[1] + pq[2] + pq[3];
    float mu = s * (1.0f / DD);
    float var = qq * (1.0f / DD) - mu * mu;
    mu_s = mu;
    rs_s = rsqrtf(var + LN_EPS);
  }
  __syncthreads();
  const float mu = mu_s, rs = rs_s;
  float4 g4 = *(const float4*)&g[tid * 4];
  float4 b4 = *(const float4*)&bta[tid * 4];
  float4 ov;
  ov.x = (v.x - mu) * rs * g4.x + b4.x;
  ov.y = (v.y - mu) * rs * g4.y + b4.y;
  ov.z = (v.z - mu) * rs * g4.z + b4.z;
  ov.w = (v.w - mu) * rs * g4.w + b4.w;
  *(float4*)&Y[(size_t)r * DD + tid * 4] = ov;
}

// ---------------------------------------------------------------------------
extern "C" void kernel_launch(void* const* d_in, const int* in_sizes, int n_in,
                              void* d_out, int out_size, void* d_ws, size_t ws_size,
                              hipStream_t stream) {
  const float* x      = (const float*)d_in[0];
  const float* W_attn = (const float*)d_in[1];
  const float* b_attn = (const float*)d_in[2];
  const float* W_out  = (const float*)d_in[3];
  const float* b_out  = (const float*)d_in[4];
  const float* ln_g   = (const float*)d_in[5];
  const float* ln_b   = (const float*)d_in[6];
  const int*   mask   = (const int*)d_in[7];
  float* out = (float*)d_out;
  ushort_t* ws = (ushort_t*)d_ws;

  ushort_t* xb    = ws;                                   // [4096][1024] bf16
  ushort_t* watt  = xb + (size_t)BB * SS * DD;            // [3072][1024] W_attn^T
  ushort_t* wot   = watt + (size_t)N3 * DD;               // [1024][1024] W_out^T
  ushort_t* qh    = wot + (size_t)DD * DD;                // [B,H,S,DH]
  ushort_t* kh    = qh + (size_t)PLANE;                   // [B,H,S,DH]
  ushort_t* vh    = kh + (size_t)PLANE;                   // [B,H,S,DH]
  ushort_t* attnb = vh + (size_t)PLANE;                   // [4096][1024]
  u32* mbits      = (u32*)(attnb + (size_t)BB * SS * DD); // 1 MB packed mask

  // 0) fused prep: x cast + both weight transposes + mask bit-pack
  prep_kernel<<<dim3(PREP_TOTAL_B), 256, 0, stream>>>(
      x, xb, W_attn, watt, W_out, wot, mask, (unsigned long long*)mbits);

  // 1) QKV projection (bf16 MFMA, C^T epilogue) -> bf16 head-major q/k/v
  gemm_qkv_mfma<<<dim3(N3 / 128, (BB * SS) / 128), 256, 0, stream>>>(
      xb, watt, b_attn, qh);
  // 2) bf16 MFMA flash attention (S^T scores, packed Pt writes)
  attn_mfma_kernel<<<dim3(BB * HH * (SS / 128)), 512, 0, stream>>>(
      qh, kh, vh, mbits, attnb);
  // 3) out projection + bias + residual (bf16 MFMA, C^T epilogue) -> fp32 d_out
  gemm_proj_mfma<<<dim3(DD / 128, (BB * SS) / 128), 256, 0, stream>>>(
      attnb, wot, b_out, x, out);
  // 4) in-place LayerNorm
  ln_kernel<<<dim3(BB * SS), 256, 0, stream>>>(out, ln_g, ln_b);
}